// Round 5
// baseline (284.040 us; speedup 1.0000x reference)
//
#include <hip/hip_runtime.h>

#define NN 50000      // nodes
#define NE 800000     // edges
#define F  64         // feature dim
#define AT 68         // padded LDS stride (mult of 4, not mult of 32)
#define SCAN_B 49     // scan blocks: 49 * 1024 >= 50000

// bf16 round-to-nearest-even, returns low-16 bits
__device__ __forceinline__ unsigned bf16rne(float f) {
    unsigned u = __float_as_uint(f);
    return (u + 0x7fffu + ((u >> 16) & 1u)) >> 16;
}
__device__ __forceinline__ float bflo(unsigned p) { return __uint_as_float(p << 16); }
__device__ __forceinline__ float bfhi(unsigned p) { return __uint_as_float(p & 0xffff0000u); }

// ---------------- CSR build ----------------

__global__ void k_count(const int* __restrict__ dst, int* __restrict__ cnt) {
    int e = blockIdx.x * blockDim.x + threadIdx.x;
    if (e < NE) atomicAdd(&cnt[dst[e]], 1);
}

// ---- 3-phase multi-block exclusive scan of cnt[0..NN) -> offs[0..NN] ----

__launch_bounds__(256)
__global__ void k_scan_a(const int* __restrict__ cnt, int* __restrict__ partials) {
    __shared__ int sc[256];
    int t = threadIdx.x;
    int base = blockIdx.x * 1024 + t * 4;
    int s = 0;
#pragma unroll
    for (int k = 0; k < 4; ++k) {
        int idx = base + k;
        s += (idx < NN) ? cnt[idx] : 0;
    }
    sc[t] = s;
    __syncthreads();
    for (int d = 128; d > 0; d >>= 1) {
        if (t < d) sc[t] += sc[t + d];
        __syncthreads();
    }
    if (t == 0) partials[blockIdx.x] = sc[0];
}

__launch_bounds__(64)
__global__ void k_scan_b(const int* __restrict__ partials, int* __restrict__ blockoff,
                         int* __restrict__ offs_last) {
    int t = threadIdx.x;
    int v = (t < SCAN_B) ? partials[t] : 0;
    int orig = v;
    for (int d = 1; d < 64; d <<= 1) {
        int u = __shfl_up(v, d);
        if (t >= d) v += u;
    }
    if (t < SCAN_B) blockoff[t] = v - orig;  // exclusive
    if (t == 63) *offs_last = v;             // total = offs[NN]
}

__launch_bounds__(256)
__global__ void k_scan_c(const int* __restrict__ cnt, const int* __restrict__ blockoff,
                         int* __restrict__ offs) {
    __shared__ int sc[256];
    int t = threadIdx.x;
    int base = blockIdx.x * 1024 + t * 4;
    int v[4];
#pragma unroll
    for (int k = 0; k < 4; ++k) {
        int idx = base + k;
        v[k] = (idx < NN) ? cnt[idx] : 0;
    }
    int lsum = v[0] + v[1] + v[2] + v[3];
    sc[t] = lsum;
    __syncthreads();
    for (int d = 1; d < 256; d <<= 1) {
        int u = (t >= d) ? sc[t - d] : 0;
        __syncthreads();
        sc[t] += u;
        __syncthreads();
    }
    int run = blockoff[blockIdx.x] + sc[t] - lsum;
#pragma unroll
    for (int k = 0; k < 4; ++k) {
        int idx = base + k;
        if (idx < NN) { offs[idx] = run; run += v[k]; }
    }
}

// fill via cursor atomics (cursor pre-seeded with a copy of offs)
__global__ void k_fill(const int* __restrict__ src, const int* __restrict__ dst,
                       int* __restrict__ cursor, int* __restrict__ csr) {
    int e = blockIdx.x * blockDim.x + threadIdx.x;
    if (e < NE) {
        int p = atomicAdd(&cursor[dst[e]], 1);
        csr[p] = src[e];
    }
}

// ---------------- embedding gather: emit bf16 table only ----------------

__global__ void k_gather(const float* __restrict__ embed, const int* __restrict__ ids,
                         uint2* __restrict__ xb) {
    int t = blockIdx.x * blockDim.x + threadIdx.x;  // over NN*16 float4s
    if (t < NN * 16) {
        int i = t >> 4, c = t & 15;
        float4 v = ((const float4*)embed)[ids[i] * 16 + c];
        uint2 p;
        p.x = bf16rne(v.x) | (bf16rne(v.y) << 16);
        p.y = bf16rne(v.z) | (bf16rne(v.w) << 16);
        xb[t] = p;
    }
}

// ---------------- neighbor mean-aggregation over bf16 table ----------------
// 8 lanes per node, each lane owns one uint4 (8 bf16) chunk of the 128 B row.
// csr indices loaded once per lane and shfl-broadcast within the 8-lane group.
// fp32 accumulation; bf16 output.

__device__ __forceinline__ void add8(float s[8], const uint4 v) {
    s[0] += bflo(v.x); s[1] += bfhi(v.x);
    s[2] += bflo(v.y); s[3] += bfhi(v.y);
    s[4] += bflo(v.z); s[5] += bfhi(v.z);
    s[6] += bflo(v.w); s[7] += bfhi(v.w);
}

__launch_bounds__(256)
__global__ void k_aggb(const uint4* __restrict__ inb, const int* __restrict__ offs,
                       const int* __restrict__ csr, uint4* __restrict__ hnb) {
    int g = (blockIdx.x * 256 + threadIdx.x) >> 3;  // node
    int c = threadIdx.x & 7;                        // uint4 chunk within row
    if (g >= NN) return;
    int lane = threadIdx.x & 63;
    int base = lane & 56;                           // first lane of this node's group
    int beg = offs[g], end = offs[g + 1];
    float s[8] = {0.f, 0.f, 0.f, 0.f, 0.f, 0.f, 0.f, 0.f};
    int j = beg;
    for (; j + 8 <= end; j += 8) {
        int v = csr[j + c];  // one load instruction covers the group's 8 indices
        int i0 = __shfl(v, base + 0, 64), i1 = __shfl(v, base + 1, 64);
        int i2 = __shfl(v, base + 2, 64), i3 = __shfl(v, base + 3, 64);
        int i4 = __shfl(v, base + 4, 64), i5 = __shfl(v, base + 5, 64);
        int i6 = __shfl(v, base + 6, 64), i7 = __shfl(v, base + 7, 64);
        uint4 d0 = inb[i0 * 8 + c], d1 = inb[i1 * 8 + c];
        uint4 d2 = inb[i2 * 8 + c], d3 = inb[i3 * 8 + c];
        uint4 d4 = inb[i4 * 8 + c], d5 = inb[i5 * 8 + c];
        uint4 d6 = inb[i6 * 8 + c], d7 = inb[i7 * 8 + c];
        add8(s, d0); add8(s, d1); add8(s, d2); add8(s, d3);
        add8(s, d4); add8(s, d5); add8(s, d6); add8(s, d7);
    }
    int rem = end - j;
    if (rem > 0) {
        int v = csr[j + (c < rem ? c : 0)];
        int idx[8];
#pragma unroll
        for (int k = 0; k < 8; ++k) idx[k] = __shfl(v, base + k, 64);
#pragma unroll
        for (int k = 0; k < 8; ++k)
            if (k < rem) { uint4 d = inb[idx[k] * 8 + c]; add8(s, d); }
    }
    int deg = end - beg;
    float inv = (deg > 0) ? 1.f / (float)deg : 0.f;
    uint4 o;
    o.x = bf16rne(s[0] * inv) | (bf16rne(s[1] * inv) << 16);
    o.y = bf16rne(s[2] * inv) | (bf16rne(s[3] * inv) << 16);
    o.z = bf16rne(s[4] * inv) | (bf16rne(s[5] * inv) << 16);
    o.w = bf16rne(s[6] * inv) | (bf16rne(s[7] * inv) << 16);
    hnb[g * 8 + c] = o;
}

// ---------------- layer GEMM: out = act(A@Ws + Nh@Wn + b) ----------------
// A-tile: from X[node] (fp32), or gathered embed[ids[node]] when ids != null.
// Nh read as bf16. EMITB: also emit bf16 copy of output for next aggregation.

template <bool RELU, bool EMITB>
__launch_bounds__(256)
__global__ void k_layer2(const float* __restrict__ X, const int* __restrict__ ids,
                         const uint4* __restrict__ Nhb,
                         const float* __restrict__ Ws, const float* __restrict__ Wn,
                         const float* __restrict__ b, float* __restrict__ out,
                         uint2* __restrict__ outb) {
    __shared__ alignas(16) float AsT[F * AT];  // transposed: [k][node]
    __shared__ alignas(16) float NsT[F * AT];
    __shared__ alignas(16) float WsL[F * F];
    __shared__ alignas(16) float WnL[F * F];

    const int tid = threadIdx.x;
    const int node0 = blockIdx.x * 64;

    for (int idx = tid; idx < F * F / 4; idx += 256) {
        ((float4*)WsL)[idx] = ((const float4*)Ws)[idx];
        ((float4*)WnL)[idx] = ((const float4*)Wn)[idx];
    }
    // A-tile: 64 nodes x 16 float4 chunks
    for (int idx = tid; idx < 64 * 16; idx += 256) {
        int n = idx >> 4, c = idx & 15;
        int node = node0 + n;
        float4 a = make_float4(0.f, 0.f, 0.f, 0.f);
        if (node < NN) {
            int row = ids ? ids[node] : node;
            a = ((const float4*)X)[row * 16 + c];
        }
        int f = 4 * c;
        AsT[(f + 0) * AT + n] = a.x; AsT[(f + 1) * AT + n] = a.y;
        AsT[(f + 2) * AT + n] = a.z; AsT[(f + 3) * AT + n] = a.w;
    }
    // N-tile: 64 nodes x 8 uint4 chunks (bf16)
    for (int idx = tid; idx < 64 * 8; idx += 256) {
        int n = idx >> 3, c = idx & 7;
        int node = node0 + n;
        uint4 v = make_uint4(0u, 0u, 0u, 0u);
        if (node < NN) v = Nhb[node * 8 + c];
        int f = 8 * c;
        NsT[(f + 0) * AT + n] = bflo(v.x); NsT[(f + 1) * AT + n] = bfhi(v.x);
        NsT[(f + 2) * AT + n] = bflo(v.y); NsT[(f + 3) * AT + n] = bfhi(v.y);
        NsT[(f + 4) * AT + n] = bflo(v.z); NsT[(f + 5) * AT + n] = bfhi(v.z);
        NsT[(f + 6) * AT + n] = bflo(v.w); NsT[(f + 7) * AT + n] = bfhi(v.w);
    }
    __syncthreads();

    const int tx = tid & 15, ty = tid >> 4;
    float acc[4][4];
#pragma unroll
    for (int j = 0; j < 4; ++j) {
        float bv = b[4 * tx + j];
        acc[0][j] = bv; acc[1][j] = bv; acc[2][j] = bv; acc[3][j] = bv;
    }
#pragma unroll 4
    for (int k = 0; k < 64; ++k) {
        float4 a4 = *(const float4*)&AsT[k * AT + 4 * ty];
        float4 n4 = *(const float4*)&NsT[k * AT + 4 * ty];
        float4 w4 = *(const float4*)&WsL[k * 64 + 4 * tx];
        float4 u4 = *(const float4*)&WnL[k * 64 + 4 * tx];
        float a_[4] = {a4.x, a4.y, a4.z, a4.w};
        float n_[4] = {n4.x, n4.y, n4.z, n4.w};
        float w_[4] = {w4.x, w4.y, w4.z, w4.w};
        float u_[4] = {u4.x, u4.y, u4.z, u4.w};
#pragma unroll
        for (int i = 0; i < 4; ++i)
#pragma unroll
            for (int j = 0; j < 4; ++j)
                acc[i][j] += a_[i] * w_[j] + n_[i] * u_[j];
    }

#pragma unroll
    for (int i = 0; i < 4; ++i) {
        int node = node0 + 4 * ty + i;
        if (node < NN) {
            float4 o;
            o.x = acc[i][0]; o.y = acc[i][1]; o.z = acc[i][2]; o.w = acc[i][3];
            if (RELU) {
                o.x = o.x > 0.f ? o.x : 0.f;
                o.y = o.y > 0.f ? o.y : 0.f;
                o.z = o.z > 0.f ? o.z : 0.f;
                o.w = o.w > 0.f ? o.w : 0.f;
            }
            *(float4*)&out[node * 64 + 4 * tx] = o;
            if (EMITB) {
                uint2 p;
                p.x = bf16rne(o.x) | (bf16rne(o.y) << 16);
                p.y = bf16rne(o.z) | (bf16rne(o.w) << 16);
                outb[node * 16 + tx] = p;
            }
        }
    }
}

// ---------------- final linear: out = H @ W_fc + b_fc ----------------

__launch_bounds__(256)
__global__ void k_final(const float* __restrict__ X, const float* __restrict__ W,
                        const float* __restrict__ b, float* __restrict__ out) {
    __shared__ alignas(16) float AsT[F * AT];
    __shared__ alignas(16) float WL[F * F];

    const int tid = threadIdx.x;
    const int node0 = blockIdx.x * 64;

    for (int idx = tid; idx < F * F / 4; idx += 256)
        ((float4*)WL)[idx] = ((const float4*)W)[idx];
    for (int idx = tid; idx < 64 * 16; idx += 256) {
        int n = idx >> 4, c = idx & 15;
        int node = node0 + n;
        float4 a = make_float4(0.f, 0.f, 0.f, 0.f);
        if (node < NN) a = ((const float4*)X)[node * 16 + c];
        int f = 4 * c;
        AsT[(f + 0) * AT + n] = a.x; AsT[(f + 1) * AT + n] = a.y;
        AsT[(f + 2) * AT + n] = a.z; AsT[(f + 3) * AT + n] = a.w;
    }
    __syncthreads();

    const int tx = tid & 15, ty = tid >> 4;
    float acc[4][4];
#pragma unroll
    for (int j = 0; j < 4; ++j) {
        float bv = b[4 * tx + j];
        acc[0][j] = bv; acc[1][j] = bv; acc[2][j] = bv; acc[3][j] = bv;
    }
#pragma unroll 4
    for (int k = 0; k < 64; ++k) {
        float4 a4 = *(const float4*)&AsT[k * AT + 4 * ty];
        float4 w4 = *(const float4*)&WL[k * 64 + 4 * tx];
        float a_[4] = {a4.x, a4.y, a4.z, a4.w};
        float w_[4] = {w4.x, w4.y, w4.z, w4.w};
#pragma unroll
        for (int i = 0; i < 4; ++i)
#pragma unroll
            for (int j = 0; j < 4; ++j)
                acc[i][j] += a_[i] * w_[j];
    }
#pragma unroll
    for (int i = 0; i < 4; ++i) {
        int node = node0 + 4 * ty + i;
        if (node < NN) {
            float4 o;
            o.x = acc[i][0]; o.y = acc[i][1]; o.z = acc[i][2]; o.w = acc[i][3];
            *(float4*)&out[node * 64 + 4 * tx] = o;
        }
    }
}

// ---------------- launch ----------------

extern "C" void kernel_launch(void* const* d_in, const int* in_sizes, int n_in,
                              void* d_out, int out_size, void* d_ws, size_t ws_size,
                              hipStream_t stream) {
    const float* embed = (const float*)d_in[0];
    const float* W1s = (const float*)d_in[1];
    const float* W1n = (const float*)d_in[2];
    const float* b1  = (const float*)d_in[3];
    const float* W2s = (const float*)d_in[4];
    const float* W2n = (const float*)d_in[5];
    const float* b2  = (const float*)d_in[6];
    const float* Wfc = (const float*)d_in[7];
    const float* bfc = (const float*)d_in[8];
    const int* ids = (const int*)d_in[9];
    const int* src = (const int*)d_in[10];
    const int* dst = (const int*)d_in[11];
    float* out = (float*)d_out;

    char* ws = (char*)d_ws;
    size_t off = 0;
    auto alloc = [&](size_t nb) {
        char* p = ws + off;
        off = (off + nb + 255) & ~(size_t)255;
        return p;
    };
    int*   cnt      = (int*)alloc(NN * sizeof(int));        // needs zero
    size_t zero_bytes = off;
    int*   offs     = (int*)alloc((NN + 1) * sizeof(int));
    int*   cursor   = (int*)alloc(NN * sizeof(int));
    int*   partials = (int*)alloc(SCAN_B * sizeof(int));
    int*   blockoff = (int*)alloc(SCAN_B * sizeof(int));
    int*   csr      = (int*)alloc(NE * sizeof(int));
    uint2* xb       = (uint2*)alloc((size_t)NN * 16 * sizeof(uint2));  // bf16 x
    uint2* h1b      = (uint2*)alloc((size_t)NN * 16 * sizeof(uint2));  // bf16 h1
    uint4* hnb      = (uint4*)alloc((size_t)NN * 8 * sizeof(uint4));   // bf16 agg
    float* h1       = (float*)alloc((size_t)NN * F * sizeof(float));
    float* h2       = (float*)alloc((size_t)NN * F * sizeof(float));

    hipMemsetAsync(d_ws, 0, zero_bytes, stream);

    const int TB = 256;
    k_count<<<(NE + TB - 1) / TB, TB, 0, stream>>>(dst, cnt);
    k_scan_a<<<SCAN_B, 256, 0, stream>>>(cnt, partials);
    k_scan_b<<<1, 64, 0, stream>>>(partials, blockoff, &offs[NN]);
    k_scan_c<<<SCAN_B, 256, 0, stream>>>(cnt, blockoff, offs);
    hipMemcpyAsync(cursor, offs, NN * sizeof(int), hipMemcpyDeviceToDevice, stream);
    k_fill<<<(NE + TB - 1) / TB, TB, 0, stream>>>(src, dst, cursor, csr);
    k_gather<<<(NN * 16 + TB - 1) / TB, TB, 0, stream>>>(embed, ids, xb);

    const int NB = (NN + 63) / 64;       // 782
    const int AB = (NN * 8 + 255) / 256; // 1563

    k_aggb<<<AB, TB, 0, stream>>>((const uint4*)xb, offs, csr, hnb);
    k_layer2<true, true><<<NB, TB, 0, stream>>>(embed, ids, hnb, W1s, W1n, b1, h1, h1b);
    k_aggb<<<AB, TB, 0, stream>>>((const uint4*)h1b, offs, csr, hnb);
    k_layer2<false, false><<<NB, TB, 0, stream>>>(h1, nullptr, hnb, W2s, W2n, b2, h2, nullptr);
    k_final<<<NB, TB, 0, stream>>>(h2, Wfc, bfc, out);
}

// Round 6
// 243.058 us; speedup vs baseline: 1.1686x; 1.1686x over previous
//
#include <hip/hip_runtime.h>

#define NN 50000      // nodes
#define NE 800000     // edges
#define F  64         // feature dim
#define AT 68         // padded LDS stride (mult of 4, not mult of 32)
#define SCAN_B 49     // scan blocks: 49 * 1024 >= 50000

// bf16 round-to-nearest-even, returns low-16 bits
__device__ __forceinline__ unsigned bf16rne(float f) {
    unsigned u = __float_as_uint(f);
    return (u + 0x7fffu + ((u >> 16) & 1u)) >> 16;
}
__device__ __forceinline__ float bflo(unsigned p) { return __uint_as_float(p << 16); }
__device__ __forceinline__ float bfhi(unsigned p) { return __uint_as_float(p & 0xffff0000u); }

// ---------------- CSR build (R4 scheme: contended atomic decoupled from scatter) ----------------

__global__ void k_count_pos(const int* __restrict__ dst, int* __restrict__ cnt,
                            int* __restrict__ pos) {
    int e = blockIdx.x * blockDim.x + threadIdx.x;
    if (e < NE) pos[e] = atomicAdd(&cnt[dst[e]], 1);  // coalesced pos write; atomic latency hidden by TLP
}

// ---- 3-phase multi-block exclusive scan of cnt[0..NN) -> offs[0..NN] ----

__launch_bounds__(256)
__global__ void k_scan_a(const int* __restrict__ cnt, int* __restrict__ partials) {
    __shared__ int sc[256];
    int t = threadIdx.x;
    int base = blockIdx.x * 1024 + t * 4;
    int s = 0;
#pragma unroll
    for (int k = 0; k < 4; ++k) {
        int idx = base + k;
        s += (idx < NN) ? cnt[idx] : 0;
    }
    sc[t] = s;
    __syncthreads();
    for (int d = 128; d > 0; d >>= 1) {
        if (t < d) sc[t] += sc[t + d];
        __syncthreads();
    }
    if (t == 0) partials[blockIdx.x] = sc[0];
}

__launch_bounds__(64)
__global__ void k_scan_b(const int* __restrict__ partials, int* __restrict__ blockoff,
                         int* __restrict__ offs_last) {
    int t = threadIdx.x;
    int v = (t < SCAN_B) ? partials[t] : 0;
    int orig = v;
    for (int d = 1; d < 64; d <<= 1) {
        int u = __shfl_up(v, d);
        if (t >= d) v += u;
    }
    if (t < SCAN_B) blockoff[t] = v - orig;  // exclusive
    if (t == 63) *offs_last = v;             // total = offs[NN]
}

__launch_bounds__(256)
__global__ void k_scan_c(const int* __restrict__ cnt, const int* __restrict__ blockoff,
                         int* __restrict__ offs) {
    __shared__ int sc[256];
    int t = threadIdx.x;
    int base = blockIdx.x * 1024 + t * 4;
    int v[4];
#pragma unroll
    for (int k = 0; k < 4; ++k) {
        int idx = base + k;
        v[k] = (idx < NN) ? cnt[idx] : 0;
    }
    int lsum = v[0] + v[1] + v[2] + v[3];
    sc[t] = lsum;
    __syncthreads();
    for (int d = 1; d < 256; d <<= 1) {
        int u = (t >= d) ? sc[t - d] : 0;
        __syncthreads();
        sc[t] += u;
        __syncthreads();
    }
    int run = blockoff[blockIdx.x] + sc[t] - lsum;
#pragma unroll
    for (int k = 0; k < 4; ++k) {
        int idx = base + k;
        if (idx < NN) { offs[idx] = run; run += v[k]; }
    }
}

// atomic-free fill: slot was precomputed in pos[]
__global__ void k_fill(const int* __restrict__ src, const int* __restrict__ dst,
                       const int* __restrict__ offs, const int* __restrict__ pos,
                       int* __restrict__ csr) {
    int e = blockIdx.x * blockDim.x + threadIdx.x;
    if (e < NE) csr[offs[dst[e]] + pos[e]] = src[e];
}

// ---------------- embedding gather: emit bf16 table only ----------------

__global__ void k_gather(const float* __restrict__ embed, const int* __restrict__ ids,
                         uint2* __restrict__ xb) {
    int t = blockIdx.x * blockDim.x + threadIdx.x;  // over NN*16 float4s
    if (t < NN * 16) {
        int i = t >> 4, c = t & 15;
        float4 v = ((const float4*)embed)[ids[i] * 16 + c];
        uint2 p;
        p.x = bf16rne(v.x) | (bf16rne(v.y) << 16);
        p.y = bf16rne(v.z) | (bf16rne(v.w) << 16);
        xb[t] = p;
    }
}

// ---------------- neighbor mean-aggregation over bf16 table ----------------
// 8 lanes per node, each lane owns one uint4 (8 bf16) chunk of the 128 B row.
// csr indices loaded once per lane and shfl-broadcast within the 8-lane group.
// fp32 accumulation; bf16 output.

__device__ __forceinline__ void add8(float s[8], const uint4 v) {
    s[0] += bflo(v.x); s[1] += bfhi(v.x);
    s[2] += bflo(v.y); s[3] += bfhi(v.y);
    s[4] += bflo(v.z); s[5] += bfhi(v.z);
    s[6] += bflo(v.w); s[7] += bfhi(v.w);
}

__launch_bounds__(256)
__global__ void k_aggb(const uint4* __restrict__ inb, const int* __restrict__ offs,
                       const int* __restrict__ csr, uint4* __restrict__ hnb) {
    int g = (blockIdx.x * 256 + threadIdx.x) >> 3;  // node
    int c = threadIdx.x & 7;                        // uint4 chunk within row
    if (g >= NN) return;
    int lane = threadIdx.x & 63;
    int base = lane & 56;                           // first lane of this node's group
    int beg = offs[g], end = offs[g + 1];
    float s[8] = {0.f, 0.f, 0.f, 0.f, 0.f, 0.f, 0.f, 0.f};
    int j = beg;
    for (; j + 8 <= end; j += 8) {
        int v = csr[j + c];  // one load instruction covers the group's 8 indices
        int i0 = __shfl(v, base + 0, 64), i1 = __shfl(v, base + 1, 64);
        int i2 = __shfl(v, base + 2, 64), i3 = __shfl(v, base + 3, 64);
        int i4 = __shfl(v, base + 4, 64), i5 = __shfl(v, base + 5, 64);
        int i6 = __shfl(v, base + 6, 64), i7 = __shfl(v, base + 7, 64);
        uint4 d0 = inb[i0 * 8 + c], d1 = inb[i1 * 8 + c];
        uint4 d2 = inb[i2 * 8 + c], d3 = inb[i3 * 8 + c];
        uint4 d4 = inb[i4 * 8 + c], d5 = inb[i5 * 8 + c];
        uint4 d6 = inb[i6 * 8 + c], d7 = inb[i7 * 8 + c];
        add8(s, d0); add8(s, d1); add8(s, d2); add8(s, d3);
        add8(s, d4); add8(s, d5); add8(s, d6); add8(s, d7);
    }
    int rem = end - j;
    if (rem > 0) {
        int v = csr[j + (c < rem ? c : 0)];
        int idx[8];
#pragma unroll
        for (int k = 0; k < 8; ++k) idx[k] = __shfl(v, base + k, 64);
#pragma unroll
        for (int k = 0; k < 8; ++k)
            if (k < rem) { uint4 d = inb[idx[k] * 8 + c]; add8(s, d); }
    }
    int deg = end - beg;
    float inv = (deg > 0) ? 1.f / (float)deg : 0.f;
    uint4 o;
    o.x = bf16rne(s[0] * inv) | (bf16rne(s[1] * inv) << 16);
    o.y = bf16rne(s[2] * inv) | (bf16rne(s[3] * inv) << 16);
    o.z = bf16rne(s[4] * inv) | (bf16rne(s[5] * inv) << 16);
    o.w = bf16rne(s[6] * inv) | (bf16rne(s[7] * inv) << 16);
    hnb[g * 8 + c] = o;
}

// ---------------- layer GEMM: out = act(A@Ws + Nh@Wn + b) ----------------
// A-tile: from X[node] (fp32), or gathered embed[ids[node]] when ids != null.
// Nh read as bf16. EMITB: also emit bf16 copy of output for next aggregation.

template <bool RELU, bool EMITB>
__launch_bounds__(256)
__global__ void k_layer2(const float* __restrict__ X, const int* __restrict__ ids,
                         const uint4* __restrict__ Nhb,
                         const float* __restrict__ Ws, const float* __restrict__ Wn,
                         const float* __restrict__ b, float* __restrict__ out,
                         uint2* __restrict__ outb) {
    __shared__ alignas(16) float AsT[F * AT];  // transposed: [k][node]
    __shared__ alignas(16) float NsT[F * AT];
    __shared__ alignas(16) float WsL[F * F];
    __shared__ alignas(16) float WnL[F * F];

    const int tid = threadIdx.x;
    const int node0 = blockIdx.x * 64;

    for (int idx = tid; idx < F * F / 4; idx += 256) {
        ((float4*)WsL)[idx] = ((const float4*)Ws)[idx];
        ((float4*)WnL)[idx] = ((const float4*)Wn)[idx];
    }
    // A-tile: 64 nodes x 16 float4 chunks
    for (int idx = tid; idx < 64 * 16; idx += 256) {
        int n = idx >> 4, c = idx & 15;
        int node = node0 + n;
        float4 a = make_float4(0.f, 0.f, 0.f, 0.f);
        if (node < NN) {
            int row = ids ? ids[node] : node;
            a = ((const float4*)X)[row * 16 + c];
        }
        int f = 4 * c;
        AsT[(f + 0) * AT + n] = a.x; AsT[(f + 1) * AT + n] = a.y;
        AsT[(f + 2) * AT + n] = a.z; AsT[(f + 3) * AT + n] = a.w;
    }
    // N-tile: 64 nodes x 8 uint4 chunks (bf16)
    for (int idx = tid; idx < 64 * 8; idx += 256) {
        int n = idx >> 3, c = idx & 7;
        int node = node0 + n;
        uint4 v = make_uint4(0u, 0u, 0u, 0u);
        if (node < NN) v = Nhb[node * 8 + c];
        int f = 8 * c;
        NsT[(f + 0) * AT + n] = bflo(v.x); NsT[(f + 1) * AT + n] = bfhi(v.x);
        NsT[(f + 2) * AT + n] = bflo(v.y); NsT[(f + 3) * AT + n] = bfhi(v.y);
        NsT[(f + 4) * AT + n] = bflo(v.z); NsT[(f + 5) * AT + n] = bfhi(v.z);
        NsT[(f + 6) * AT + n] = bflo(v.w); NsT[(f + 7) * AT + n] = bfhi(v.w);
    }
    __syncthreads();

    const int tx = tid & 15, ty = tid >> 4;
    float acc[4][4];
#pragma unroll
    for (int j = 0; j < 4; ++j) {
        float bv = b[4 * tx + j];
        acc[0][j] = bv; acc[1][j] = bv; acc[2][j] = bv; acc[3][j] = bv;
    }
#pragma unroll 4
    for (int k = 0; k < 64; ++k) {
        float4 a4 = *(const float4*)&AsT[k * AT + 4 * ty];
        float4 n4 = *(const float4*)&NsT[k * AT + 4 * ty];
        float4 w4 = *(const float4*)&WsL[k * 64 + 4 * tx];
        float4 u4 = *(const float4*)&WnL[k * 64 + 4 * tx];
        float a_[4] = {a4.x, a4.y, a4.z, a4.w};
        float n_[4] = {n4.x, n4.y, n4.z, n4.w};
        float w_[4] = {w4.x, w4.y, w4.z, w4.w};
        float u_[4] = {u4.x, u4.y, u4.z, u4.w};
#pragma unroll
        for (int i = 0; i < 4; ++i)
#pragma unroll
            for (int j = 0; j < 4; ++j)
                acc[i][j] += a_[i] * w_[j] + n_[i] * u_[j];
    }

#pragma unroll
    for (int i = 0; i < 4; ++i) {
        int node = node0 + 4 * ty + i;
        if (node < NN) {
            float4 o;
            o.x = acc[i][0]; o.y = acc[i][1]; o.z = acc[i][2]; o.w = acc[i][3];
            if (RELU) {
                o.x = o.x > 0.f ? o.x : 0.f;
                o.y = o.y > 0.f ? o.y : 0.f;
                o.z = o.z > 0.f ? o.z : 0.f;
                o.w = o.w > 0.f ? o.w : 0.f;
            }
            *(float4*)&out[node * 64 + 4 * tx] = o;
            if (EMITB) {
                uint2 p;
                p.x = bf16rne(o.x) | (bf16rne(o.y) << 16);
                p.y = bf16rne(o.z) | (bf16rne(o.w) << 16);
                outb[node * 16 + tx] = p;
            }
        }
    }
}

// ---------------- final linear: out = H @ W_fc + b_fc ----------------

__launch_bounds__(256)
__global__ void k_final(const float* __restrict__ X, const float* __restrict__ W,
                        const float* __restrict__ b, float* __restrict__ out) {
    __shared__ alignas(16) float AsT[F * AT];
    __shared__ alignas(16) float WL[F * F];

    const int tid = threadIdx.x;
    const int node0 = blockIdx.x * 64;

    for (int idx = tid; idx < F * F / 4; idx += 256)
        ((float4*)WL)[idx] = ((const float4*)W)[idx];
    for (int idx = tid; idx < 64 * 16; idx += 256) {
        int n = idx >> 4, c = idx & 15;
        int node = node0 + n;
        float4 a = make_float4(0.f, 0.f, 0.f, 0.f);
        if (node < NN) a = ((const float4*)X)[node * 16 + c];
        int f = 4 * c;
        AsT[(f + 0) * AT + n] = a.x; AsT[(f + 1) * AT + n] = a.y;
        AsT[(f + 2) * AT + n] = a.z; AsT[(f + 3) * AT + n] = a.w;
    }
    __syncthreads();

    const int tx = tid & 15, ty = tid >> 4;
    float acc[4][4];
#pragma unroll
    for (int j = 0; j < 4; ++j) {
        float bv = b[4 * tx + j];
        acc[0][j] = bv; acc[1][j] = bv; acc[2][j] = bv; acc[3][j] = bv;
    }
#pragma unroll 4
    for (int k = 0; k < 64; ++k) {
        float4 a4 = *(const float4*)&AsT[k * AT + 4 * ty];
        float4 w4 = *(const float4*)&WL[k * 64 + 4 * tx];
        float a_[4] = {a4.x, a4.y, a4.z, a4.w};
        float w_[4] = {w4.x, w4.y, w4.z, w4.w};
#pragma unroll
        for (int i = 0; i < 4; ++i)
#pragma unroll
            for (int j = 0; j < 4; ++j)
                acc[i][j] += a_[i] * w_[j];
    }
#pragma unroll
    for (int i = 0; i < 4; ++i) {
        int node = node0 + 4 * ty + i;
        if (node < NN) {
            float4 o;
            o.x = acc[i][0]; o.y = acc[i][1]; o.z = acc[i][2]; o.w = acc[i][3];
            *(float4*)&out[node * 64 + 4 * tx] = o;
        }
    }
}

// ---------------- launch ----------------

extern "C" void kernel_launch(void* const* d_in, const int* in_sizes, int n_in,
                              void* d_out, int out_size, void* d_ws, size_t ws_size,
                              hipStream_t stream) {
    const float* embed = (const float*)d_in[0];
    const float* W1s = (const float*)d_in[1];
    const float* W1n = (const float*)d_in[2];
    const float* b1  = (const float*)d_in[3];
    const float* W2s = (const float*)d_in[4];
    const float* W2n = (const float*)d_in[5];
    const float* b2  = (const float*)d_in[6];
    const float* Wfc = (const float*)d_in[7];
    const float* bfc = (const float*)d_in[8];
    const int* ids = (const int*)d_in[9];
    const int* src = (const int*)d_in[10];
    const int* dst = (const int*)d_in[11];
    float* out = (float*)d_out;

    char* ws = (char*)d_ws;
    size_t off = 0;
    auto alloc = [&](size_t nb) {
        char* p = ws + off;
        off = (off + nb + 255) & ~(size_t)255;
        return p;
    };
    int*   cnt      = (int*)alloc(NN * sizeof(int));        // needs zero
    size_t zero_bytes = off;
    int*   offs     = (int*)alloc((NN + 1) * sizeof(int));
    int*   partials = (int*)alloc(SCAN_B * sizeof(int));
    int*   blockoff = (int*)alloc(SCAN_B * sizeof(int));
    int*   pos      = (int*)alloc(NE * sizeof(int));
    int*   csr      = (int*)alloc(NE * sizeof(int));
    uint2* xb       = (uint2*)alloc((size_t)NN * 16 * sizeof(uint2));  // bf16 x
    uint2* h1b      = (uint2*)alloc((size_t)NN * 16 * sizeof(uint2));  // bf16 h1
    uint4* hnb      = (uint4*)alloc((size_t)NN * 8 * sizeof(uint4));   // bf16 agg
    float* h1       = (float*)alloc((size_t)NN * F * sizeof(float));
    float* h2       = (float*)alloc((size_t)NN * F * sizeof(float));

    hipMemsetAsync(d_ws, 0, zero_bytes, stream);

    const int TB = 256;
    k_count_pos<<<(NE + TB - 1) / TB, TB, 0, stream>>>(dst, cnt, pos);
    k_scan_a<<<SCAN_B, 256, 0, stream>>>(cnt, partials);
    k_scan_b<<<1, 64, 0, stream>>>(partials, blockoff, &offs[NN]);
    k_scan_c<<<SCAN_B, 256, 0, stream>>>(cnt, blockoff, offs);
    k_fill<<<(NE + TB - 1) / TB, TB, 0, stream>>>(src, dst, offs, pos, csr);
    k_gather<<<(NN * 16 + TB - 1) / TB, TB, 0, stream>>>(embed, ids, xb);

    const int NB = (NN + 63) / 64;       // 782
    const int AB = (NN * 8 + 255) / 256; // 1563

    k_aggb<<<AB, TB, 0, stream>>>((const uint4*)xb, offs, csr, hnb);
    k_layer2<true, true><<<NB, TB, 0, stream>>>(embed, ids, hnb, W1s, W1n, b1, h1, h1b);
    k_aggb<<<AB, TB, 0, stream>>>((const uint4*)h1b, offs, csr, hnb);
    k_layer2<false, false><<<NB, TB, 0, stream>>>(h1, nullptr, hnb, W2s, W2n, b2, h2, nullptr);
    k_final<<<NB, TB, 0, stream>>>(h2, Wfc, bfc, out);
}

// Round 7
// 236.020 us; speedup vs baseline: 1.2035x; 1.0298x over previous
//
#include <hip/hip_runtime.h>

#define NN 50000      // nodes
#define NE 800000     // edges
#define F  64         // feature dim
#define AT 68         // padded LDS stride (mult of 4, not mult of 32)
#define SCAN_B 49     // scan blocks: 49 * 1024 >= 50000

// bf16 round-to-nearest-even, returns low-16 bits
__device__ __forceinline__ unsigned bf16rne(float f) {
    unsigned u = __float_as_uint(f);
    return (u + 0x7fffu + ((u >> 16) & 1u)) >> 16;
}
__device__ __forceinline__ float bflo(unsigned p) { return __uint_as_float(p << 16); }
__device__ __forceinline__ float bfhi(unsigned p) { return __uint_as_float(p & 0xffff0000u); }

// ---------------- fused: edge degree count+slot  AND  embedding gather ----------------
// NE == NN*16 == 800000, so one 3125-block grid covers both index spaces exactly.

__launch_bounds__(256)
__global__ void k_count_gather(const int* __restrict__ dst, int* __restrict__ cnt,
                               int* __restrict__ pos,
                               const float* __restrict__ embed, const int* __restrict__ ids,
                               uint2* __restrict__ xb) {
    int t = blockIdx.x * blockDim.x + threadIdx.x;
    if (t < NE) pos[t] = atomicAdd(&cnt[dst[t]], 1);   // coalesced pos write
    if (t < NN * 16) {
        int i = t >> 4, c = t & 15;
        float4 v = ((const float4*)embed)[ids[i] * 16 + c];
        uint2 p;
        p.x = bf16rne(v.x) | (bf16rne(v.y) << 16);
        p.y = bf16rne(v.z) | (bf16rne(v.w) << 16);
        xb[t] = p;
    }
}

// ---- 2-dispatch scan: block partials, then per-block redundant scan of partials ----

__launch_bounds__(256)
__global__ void k_scan_a(const int* __restrict__ cnt, int* __restrict__ partials) {
    __shared__ int sc[256];
    int t = threadIdx.x;
    int base = blockIdx.x * 1024 + t * 4;
    int s = 0;
#pragma unroll
    for (int k = 0; k < 4; ++k) {
        int idx = base + k;
        s += (idx < NN) ? cnt[idx] : 0;
    }
    sc[t] = s;
    __syncthreads();
    for (int d = 128; d > 0; d >>= 1) {
        if (t < d) sc[t] += sc[t + d];
        __syncthreads();
    }
    if (t == 0) partials[blockIdx.x] = sc[0];
}

__launch_bounds__(256)
__global__ void k_scan_c2(const int* __restrict__ cnt, const int* __restrict__ partials,
                          int* __restrict__ offs) {
    __shared__ int sboff;   // this block's exclusive offset
    __shared__ int stotal;  // grand total (written as offs[NN] by block 0)
    __shared__ int sc[256];
    int t = threadIdx.x;
    if (t < 64) {  // wave 0 redundantly scans the 49 partials (replaces k_scan_b)
        int v = (t < SCAN_B) ? partials[t] : 0;
        int orig = v;
        for (int d = 1; d < 64; d <<= 1) {
            int u = __shfl_up(v, d);
            if (t >= d) v += u;
        }
        if (t == (int)blockIdx.x) sboff = v - orig;  // blockIdx.x < 49 < 64
        if (t == 63) stotal = v;
    }
    int base = blockIdx.x * 1024 + t * 4;
    int v4[4];
#pragma unroll
    for (int k = 0; k < 4; ++k) {
        int idx = base + k;
        v4[k] = (idx < NN) ? cnt[idx] : 0;
    }
    int lsum = v4[0] + v4[1] + v4[2] + v4[3];
    sc[t] = lsum;
    __syncthreads();
    for (int d = 1; d < 256; d <<= 1) {
        int u = (t >= d) ? sc[t - d] : 0;
        __syncthreads();
        sc[t] += u;
        __syncthreads();
    }
    int run = sboff + sc[t] - lsum;
#pragma unroll
    for (int k = 0; k < 4; ++k) {
        int idx = base + k;
        if (idx < NN) { offs[idx] = run; run += v4[k]; }
    }
    if (blockIdx.x == 0 && t == 0) offs[NN] = stotal;
}

// atomic-free fill: slot was precomputed in pos[]
__global__ void k_fill(const int* __restrict__ src, const int* __restrict__ dst,
                       const int* __restrict__ offs, const int* __restrict__ pos,
                       int* __restrict__ csr) {
    int e = blockIdx.x * blockDim.x + threadIdx.x;
    if (e < NE) csr[offs[dst[e]] + pos[e]] = src[e];
}

// ---------------- neighbor mean-aggregation over bf16 table ----------------

__device__ __forceinline__ void add8(float s[8], const uint4 v) {
    s[0] += bflo(v.x); s[1] += bfhi(v.x);
    s[2] += bflo(v.y); s[3] += bfhi(v.y);
    s[4] += bflo(v.z); s[5] += bfhi(v.z);
    s[6] += bflo(v.w); s[7] += bfhi(v.w);
}

__launch_bounds__(256)
__global__ void k_aggb(const uint4* __restrict__ inb, const int* __restrict__ offs,
                       const int* __restrict__ csr, uint4* __restrict__ hnb) {
    int g = (blockIdx.x * 256 + threadIdx.x) >> 3;  // node
    int c = threadIdx.x & 7;                        // uint4 chunk within row
    if (g >= NN) return;
    int lane = threadIdx.x & 63;
    int base = lane & 56;
    int beg = offs[g], end = offs[g + 1];
    float s[8] = {0.f, 0.f, 0.f, 0.f, 0.f, 0.f, 0.f, 0.f};
    int j = beg;
    for (; j + 8 <= end; j += 8) {
        int v = csr[j + c];
        int i0 = __shfl(v, base + 0, 64), i1 = __shfl(v, base + 1, 64);
        int i2 = __shfl(v, base + 2, 64), i3 = __shfl(v, base + 3, 64);
        int i4 = __shfl(v, base + 4, 64), i5 = __shfl(v, base + 5, 64);
        int i6 = __shfl(v, base + 6, 64), i7 = __shfl(v, base + 7, 64);
        uint4 d0 = inb[i0 * 8 + c], d1 = inb[i1 * 8 + c];
        uint4 d2 = inb[i2 * 8 + c], d3 = inb[i3 * 8 + c];
        uint4 d4 = inb[i4 * 8 + c], d5 = inb[i5 * 8 + c];
        uint4 d6 = inb[i6 * 8 + c], d7 = inb[i7 * 8 + c];
        add8(s, d0); add8(s, d1); add8(s, d2); add8(s, d3);
        add8(s, d4); add8(s, d5); add8(s, d6); add8(s, d7);
    }
    int rem = end - j;
    if (rem > 0) {
        int v = csr[j + (c < rem ? c : 0)];
        int idx[8];
#pragma unroll
        for (int k = 0; k < 8; ++k) idx[k] = __shfl(v, base + k, 64);
#pragma unroll
        for (int k = 0; k < 8; ++k)
            if (k < rem) { uint4 d = inb[idx[k] * 8 + c]; add8(s, d); }
    }
    int deg = end - beg;
    float inv = (deg > 0) ? 1.f / (float)deg : 0.f;
    uint4 o;
    o.x = bf16rne(s[0] * inv) | (bf16rne(s[1] * inv) << 16);
    o.y = bf16rne(s[2] * inv) | (bf16rne(s[3] * inv) << 16);
    o.z = bf16rne(s[4] * inv) | (bf16rne(s[5] * inv) << 16);
    o.w = bf16rne(s[6] * inv) | (bf16rne(s[7] * inv) << 16);
    hnb[g * 8 + c] = o;
}

// ---------------- layer 1: h1b = bf16(relu(embed[ids]@W1s + Nh@W1n + b1)) ----------------

__launch_bounds__(256)
__global__ void k_layer_mid(const float* __restrict__ X, const int* __restrict__ ids,
                            const uint4* __restrict__ Nhb,
                            const float* __restrict__ Ws, const float* __restrict__ Wn,
                            const float* __restrict__ b, uint2* __restrict__ outb) {
    __shared__ alignas(16) float AsT[F * AT];
    __shared__ alignas(16) float NsT[F * AT];
    __shared__ alignas(16) float WsL[F * F];
    __shared__ alignas(16) float WnL[F * F];

    const int tid = threadIdx.x;
    const int node0 = blockIdx.x * 64;

    for (int idx = tid; idx < F * F / 4; idx += 256) {
        ((float4*)WsL)[idx] = ((const float4*)Ws)[idx];
        ((float4*)WnL)[idx] = ((const float4*)Wn)[idx];
    }
    for (int idx = tid; idx < 64 * 16; idx += 256) {  // A-tile: gathered fp32
        int n = idx >> 4, c = idx & 15;
        int node = node0 + n;
        float4 a = make_float4(0.f, 0.f, 0.f, 0.f);
        if (node < NN) a = ((const float4*)X)[ids[node] * 16 + c];
        int f = 4 * c;
        AsT[(f + 0) * AT + n] = a.x; AsT[(f + 1) * AT + n] = a.y;
        AsT[(f + 2) * AT + n] = a.z; AsT[(f + 3) * AT + n] = a.w;
    }
    for (int idx = tid; idx < 64 * 8; idx += 256) {   // N-tile: bf16
        int n = idx >> 3, c = idx & 7;
        int node = node0 + n;
        uint4 v = make_uint4(0u, 0u, 0u, 0u);
        if (node < NN) v = Nhb[node * 8 + c];
        int f = 8 * c;
        NsT[(f + 0) * AT + n] = bflo(v.x); NsT[(f + 1) * AT + n] = bfhi(v.x);
        NsT[(f + 2) * AT + n] = bflo(v.y); NsT[(f + 3) * AT + n] = bfhi(v.y);
        NsT[(f + 4) * AT + n] = bflo(v.z); NsT[(f + 5) * AT + n] = bfhi(v.z);
        NsT[(f + 6) * AT + n] = bflo(v.w); NsT[(f + 7) * AT + n] = bfhi(v.w);
    }
    __syncthreads();

    const int tx = tid & 15, ty = tid >> 4;
    float acc[4][4];
#pragma unroll
    for (int j = 0; j < 4; ++j) {
        float bv = b[4 * tx + j];
        acc[0][j] = bv; acc[1][j] = bv; acc[2][j] = bv; acc[3][j] = bv;
    }
#pragma unroll 4
    for (int k = 0; k < 64; ++k) {
        float4 a4 = *(const float4*)&AsT[k * AT + 4 * ty];
        float4 n4 = *(const float4*)&NsT[k * AT + 4 * ty];
        float4 w4 = *(const float4*)&WsL[k * 64 + 4 * tx];
        float4 u4 = *(const float4*)&WnL[k * 64 + 4 * tx];
        float a_[4] = {a4.x, a4.y, a4.z, a4.w};
        float n_[4] = {n4.x, n4.y, n4.z, n4.w};
        float w_[4] = {w4.x, w4.y, w4.z, w4.w};
        float u_[4] = {u4.x, u4.y, u4.z, u4.w};
#pragma unroll
        for (int i = 0; i < 4; ++i)
#pragma unroll
            for (int j = 0; j < 4; ++j)
                acc[i][j] += a_[i] * w_[j] + n_[i] * u_[j];
    }

#pragma unroll
    for (int i = 0; i < 4; ++i) {
        int node = node0 + 4 * ty + i;
        if (node < NN) {
            float ox = acc[i][0] > 0.f ? acc[i][0] : 0.f;
            float oy = acc[i][1] > 0.f ? acc[i][1] : 0.f;
            float oz = acc[i][2] > 0.f ? acc[i][2] : 0.f;
            float ow = acc[i][3] > 0.f ? acc[i][3] : 0.f;
            uint2 p;
            p.x = bf16rne(ox) | (bf16rne(oy) << 16);
            p.y = bf16rne(oz) | (bf16rne(ow) << 16);
            outb[node * 16 + tx] = p;
        }
    }
}

// ---------------- layer 2 + final fused: out = (h1b@W2s + Nh@W2n + b2) @ Wfc + bfc ----------------

__launch_bounds__(256)
__global__ void k_layer_last(const uint4* __restrict__ Ab, const uint4* __restrict__ Nhb,
                             const float* __restrict__ Ws, const float* __restrict__ Wn,
                             const float* __restrict__ b,
                             const float* __restrict__ Wfc, const float* __restrict__ bfc,
                             float* __restrict__ out) {
    __shared__ alignas(16) float AsT[F * AT];
    __shared__ alignas(16) float NsT[F * AT];
    __shared__ alignas(16) float WsL[F * F];
    __shared__ alignas(16) float WnL[F * F];

    const int tid = threadIdx.x;
    const int node0 = blockIdx.x * 64;

    for (int idx = tid; idx < F * F / 4; idx += 256) {
        ((float4*)WsL)[idx] = ((const float4*)Ws)[idx];
        ((float4*)WnL)[idx] = ((const float4*)Wn)[idx];
    }
    for (int idx = tid; idx < 64 * 8; idx += 256) {   // A-tile from bf16 h1b
        int n = idx >> 3, c = idx & 7;
        int node = node0 + n;
        uint4 v = make_uint4(0u, 0u, 0u, 0u);
        if (node < NN) v = Ab[node * 8 + c];
        int f = 8 * c;
        AsT[(f + 0) * AT + n] = bflo(v.x); AsT[(f + 1) * AT + n] = bfhi(v.x);
        AsT[(f + 2) * AT + n] = bflo(v.y); AsT[(f + 3) * AT + n] = bfhi(v.y);
        AsT[(f + 4) * AT + n] = bflo(v.z); AsT[(f + 5) * AT + n] = bfhi(v.z);
        AsT[(f + 6) * AT + n] = bflo(v.w); AsT[(f + 7) * AT + n] = bfhi(v.w);
    }
    for (int idx = tid; idx < 64 * 8; idx += 256) {   // N-tile from bf16 hnb
        int n = idx >> 3, c = idx & 7;
        int node = node0 + n;
        uint4 v = make_uint4(0u, 0u, 0u, 0u);
        if (node < NN) v = Nhb[node * 8 + c];
        int f = 8 * c;
        NsT[(f + 0) * AT + n] = bflo(v.x); NsT[(f + 1) * AT + n] = bfhi(v.x);
        NsT[(f + 2) * AT + n] = bflo(v.y); NsT[(f + 3) * AT + n] = bfhi(v.y);
        NsT[(f + 4) * AT + n] = bflo(v.z); NsT[(f + 5) * AT + n] = bfhi(v.z);
        NsT[(f + 6) * AT + n] = bflo(v.w); NsT[(f + 7) * AT + n] = bfhi(v.w);
    }
    __syncthreads();

    const int tx = tid & 15, ty = tid >> 4;
    float acc[4][4];
#pragma unroll
    for (int j = 0; j < 4; ++j) {
        float bv = b[4 * tx + j];
        acc[0][j] = bv; acc[1][j] = bv; acc[2][j] = bv; acc[3][j] = bv;
    }
#pragma unroll 4
    for (int k = 0; k < 64; ++k) {
        float4 a4 = *(const float4*)&AsT[k * AT + 4 * ty];
        float4 n4 = *(const float4*)&NsT[k * AT + 4 * ty];
        float4 w4 = *(const float4*)&WsL[k * 64 + 4 * tx];
        float4 u4 = *(const float4*)&WnL[k * 64 + 4 * tx];
        float a_[4] = {a4.x, a4.y, a4.z, a4.w};
        float n_[4] = {n4.x, n4.y, n4.z, n4.w};
        float w_[4] = {w4.x, w4.y, w4.z, w4.w};
        float u_[4] = {u4.x, u4.y, u4.z, u4.w};
#pragma unroll
        for (int i = 0; i < 4; ++i)
#pragma unroll
            for (int j = 0; j < 4; ++j)
                acc[i][j] += a_[i] * w_[j] + n_[i] * u_[j];
    }

    // ---- fused final GEMM: h2 tile -> LDS (transposed), Wfc -> WsL, GEMM2 ----
    __syncthreads();  // all reads of AsT/WsL done
#pragma unroll
    for (int i = 0; i < 4; ++i)
#pragma unroll
        for (int j = 0; j < 4; ++j)
            AsT[(4 * tx + j) * AT + (4 * ty + i)] = acc[i][j];
    for (int idx = tid; idx < F * F / 4; idx += 256)
        ((float4*)WsL)[idx] = ((const float4*)Wfc)[idx];
    __syncthreads();

    float acc2[4][4];
#pragma unroll
    for (int j = 0; j < 4; ++j) {
        float bv = bfc[4 * tx + j];
        acc2[0][j] = bv; acc2[1][j] = bv; acc2[2][j] = bv; acc2[3][j] = bv;
    }
#pragma unroll 4
    for (int k = 0; k < 64; ++k) {
        float4 a4 = *(const float4*)&AsT[k * AT + 4 * ty];
        float4 w4 = *(const float4*)&WsL[k * 64 + 4 * tx];
        float a_[4] = {a4.x, a4.y, a4.z, a4.w};
        float w_[4] = {w4.x, w4.y, w4.z, w4.w};
#pragma unroll
        for (int i = 0; i < 4; ++i)
#pragma unroll
            for (int j = 0; j < 4; ++j)
                acc2[i][j] += a_[i] * w_[j];
    }
#pragma unroll
    for (int i = 0; i < 4; ++i) {
        int node = node0 + 4 * ty + i;
        if (node < NN) {
            float4 o;
            o.x = acc2[i][0]; o.y = acc2[i][1]; o.z = acc2[i][2]; o.w = acc2[i][3];
            *(float4*)&out[node * 64 + 4 * tx] = o;
        }
    }
}

// ---------------- launch ----------------

extern "C" void kernel_launch(void* const* d_in, const int* in_sizes, int n_in,
                              void* d_out, int out_size, void* d_ws, size_t ws_size,
                              hipStream_t stream) {
    const float* embed = (const float*)d_in[0];
    const float* W1s = (const float*)d_in[1];
    const float* W1n = (const float*)d_in[2];
    const float* b1  = (const float*)d_in[3];
    const float* W2s = (const float*)d_in[4];
    const float* W2n = (const float*)d_in[5];
    const float* b2  = (const float*)d_in[6];
    const float* Wfc = (const float*)d_in[7];
    const float* bfc = (const float*)d_in[8];
    const int* ids = (const int*)d_in[9];
    const int* src = (const int*)d_in[10];
    const int* dst = (const int*)d_in[11];
    float* out = (float*)d_out;

    char* ws = (char*)d_ws;
    size_t off = 0;
    auto alloc = [&](size_t nb) {
        char* p = ws + off;
        off = (off + nb + 255) & ~(size_t)255;
        return p;
    };
    int*   cnt      = (int*)alloc(NN * sizeof(int));        // needs zero
    size_t zero_bytes = off;
    int*   offs     = (int*)alloc((NN + 1) * sizeof(int));
    int*   partials = (int*)alloc(SCAN_B * sizeof(int));
    int*   pos      = (int*)alloc(NE * sizeof(int));
    int*   csr      = (int*)alloc(NE * sizeof(int));
    uint2* xb       = (uint2*)alloc((size_t)NN * 16 * sizeof(uint2));  // bf16 x
    uint2* h1b      = (uint2*)alloc((size_t)NN * 16 * sizeof(uint2));  // bf16 h1
    uint4* hnb      = (uint4*)alloc((size_t)NN * 8 * sizeof(uint4));   // bf16 agg

    hipMemsetAsync(d_ws, 0, zero_bytes, stream);

    const int TB = 256;
    const int EB = (NE + TB - 1) / TB;   // 3125 (== NN*16/256)
    k_count_gather<<<EB, TB, 0, stream>>>(dst, cnt, pos, embed, ids, xb);
    k_scan_a<<<SCAN_B, 256, 0, stream>>>(cnt, partials);
    k_scan_c2<<<SCAN_B, 256, 0, stream>>>(cnt, partials, offs);
    k_fill<<<EB, TB, 0, stream>>>(src, dst, offs, pos, csr);

    const int NB = (NN + 63) / 64;       // 782
    const int AB = (NN * 8 + 255) / 256; // 1563

    k_aggb<<<AB, TB, 0, stream>>>((const uint4*)xb, offs, csr, hnb);
    k_layer_mid<<<NB, TB, 0, stream>>>(embed, ids, hnb, W1s, W1n, b1, h1b);
    k_aggb<<<AB, TB, 0, stream>>>((const uint4*)h1b, offs, csr, hnb);
    k_layer_last<<<NB, TB, 0, stream>>>((const uint4*)h1b, hnb, W2s, W2n, b2, Wfc, bfc, out);
}

// Round 8
// 235.295 us; speedup vs baseline: 1.2072x; 1.0031x over previous
//
#include <hip/hip_runtime.h>

#define NN 50000      // nodes
#define NE 800000     // edges
#define F  64         // feature dim
#define AT 68         // padded LDS stride (mult of 4, not mult of 32)
#define SCAN_B 49     // scan blocks: 49 * 1024 >= 50000

// bf16 round-to-nearest-even, returns low-16 bits
__device__ __forceinline__ unsigned bf16rne(float f) {
    unsigned u = __float_as_uint(f);
    return (u + 0x7fffu + ((u >> 16) & 1u)) >> 16;
}
__device__ __forceinline__ float bflo(unsigned p) { return __uint_as_float(p << 16); }
__device__ __forceinline__ float bfhi(unsigned p) { return __uint_as_float(p & 0xffff0000u); }

// ---------------- fused: edge degree count+slot  AND  embedding gather ----------------

__launch_bounds__(256)
__global__ void k_count_gather(const int* __restrict__ dst, int* __restrict__ cnt,
                               int* __restrict__ pos,
                               const float* __restrict__ embed, const int* __restrict__ ids,
                               uint2* __restrict__ xb) {
    int t = blockIdx.x * blockDim.x + threadIdx.x;
    if (t < NE) pos[t] = atomicAdd(&cnt[dst[t]], 1);   // coalesced pos write
    if (t < NN * 16) {
        int i = t >> 4, c = t & 15;
        float4 v = ((const float4*)embed)[ids[i] * 16 + c];
        uint2 p;
        p.x = bf16rne(v.x) | (bf16rne(v.y) << 16);
        p.y = bf16rne(v.z) | (bf16rne(v.w) << 16);
        xb[t] = p;
    }
}

// ---- 2-dispatch scan; scan_c2 also builds a 64-bin degree histogram ----

__launch_bounds__(256)
__global__ void k_scan_a(const int* __restrict__ cnt, int* __restrict__ partials) {
    __shared__ int sc[256];
    int t = threadIdx.x;
    int base = blockIdx.x * 1024 + t * 4;
    int s = 0;
#pragma unroll
    for (int k = 0; k < 4; ++k) {
        int idx = base + k;
        s += (idx < NN) ? cnt[idx] : 0;
    }
    sc[t] = s;
    __syncthreads();
    for (int d = 128; d > 0; d >>= 1) {
        if (t < d) sc[t] += sc[t + d];
        __syncthreads();
    }
    if (t == 0) partials[blockIdx.x] = sc[0];
}

__launch_bounds__(256)
__global__ void k_scan_c2(const int* __restrict__ cnt, const int* __restrict__ partials,
                          int* __restrict__ offs, int* __restrict__ dhist) {
    __shared__ int sboff;
    __shared__ int stotal;
    __shared__ int sc[256];
    __shared__ int shist[64];
    int t = threadIdx.x;
    if (t < 64) {  // wave 0 redundantly scans the 49 partials
        int v = (t < SCAN_B) ? partials[t] : 0;
        int orig = v;
        for (int d = 1; d < 64; d <<= 1) {
            int u = __shfl_up(v, d);
            if (t >= d) v += u;
        }
        if (t == (int)blockIdx.x) sboff = v - orig;
        if (t == 63) stotal = v;
        shist[t] = 0;
    }
    int base = blockIdx.x * 1024 + t * 4;
    int v4[4];
#pragma unroll
    for (int k = 0; k < 4; ++k) {
        int idx = base + k;
        v4[k] = (idx < NN) ? cnt[idx] : 0;
    }
    int lsum = v4[0] + v4[1] + v4[2] + v4[3];
    sc[t] = lsum;
    __syncthreads();
#pragma unroll
    for (int k = 0; k < 4; ++k) {   // degree histogram (LDS, then one flush)
        int idx = base + k;
        if (idx < NN) atomicAdd(&shist[v4[k] < 63 ? v4[k] : 63], 1);
    }
    for (int d = 1; d < 256; d <<= 1) {
        int u = (t >= d) ? sc[t - d] : 0;
        __syncthreads();
        sc[t] += u;
        __syncthreads();
    }
    int run = sboff + sc[t] - lsum;
#pragma unroll
    for (int k = 0; k < 4; ++k) {
        int idx = base + k;
        if (idx < NN) { offs[idx] = run; run += v4[k]; }
    }
    if (blockIdx.x == 0 && t == 0) offs[NN] = stotal;
    if (t < 64 && shist[t]) atomicAdd(&dhist[t], shist[t]);
}

// ---- degree-bucket permutation: perm[] lists node ids grouped by degree ----

__launch_bounds__(256)
__global__ void k_perm(const int* __restrict__ cnt, const int* __restrict__ dhist,
                       int* __restrict__ dcur, int* __restrict__ perm) {
    __shared__ int boff[64];   // global exclusive scan of dhist
    __shared__ int bcnt[64];   // this block's histogram
    __shared__ int bbase[64];  // this block's base within each bin
    __shared__ int bcur[64];
    int t = threadIdx.x;
    int node = blockIdx.x * 256 + t;
    if (t < 64) {
        int v = dhist[t];
        int orig = v;
        for (int d = 1; d < 64; d <<= 1) {
            int u = __shfl_up(v, d);
            if (t >= d) v += u;
        }
        boff[t] = v - orig;
        bcnt[t] = 0;
        bcur[t] = 0;
    }
    __syncthreads();
    int bin = -1;
    if (node < NN) {
        int deg = cnt[node];
        bin = deg < 63 ? deg : 63;
        atomicAdd(&bcnt[bin], 1);
    }
    __syncthreads();
    if (t < 64) bbase[t] = bcnt[t] ? atomicAdd(&dcur[t], bcnt[t]) : 0;
    __syncthreads();
    if (node < NN) {
        int p = atomicAdd(&bcur[bin], 1);
        perm[boff[bin] + bbase[bin] + p] = node;
    }
}

// atomic-free fill: slot was precomputed in pos[]
__global__ void k_fill(const int* __restrict__ src, const int* __restrict__ dst,
                       const int* __restrict__ offs, const int* __restrict__ pos,
                       int* __restrict__ csr) {
    int e = blockIdx.x * blockDim.x + threadIdx.x;
    if (e < NE) csr[offs[dst[e]] + pos[e]] = src[e];
}

// ---------------- neighbor mean-aggregation over bf16 table ----------------
// 8 lanes per node (node order degree-sorted via perm -> uniform waves).
// unroll-16 main loop: 16 gathers in flight per lane.

__device__ __forceinline__ void add8(float s[8], const uint4 v) {
    s[0] += bflo(v.x); s[1] += bfhi(v.x);
    s[2] += bflo(v.y); s[3] += bfhi(v.y);
    s[4] += bflo(v.z); s[5] += bfhi(v.z);
    s[6] += bflo(v.w); s[7] += bfhi(v.w);
}

__launch_bounds__(256)
__global__ void k_aggb(const uint4* __restrict__ inb, const int* __restrict__ offs,
                       const int* __restrict__ csr, const int* __restrict__ perm,
                       uint4* __restrict__ hnb) {
    int gg = (blockIdx.x * 256 + threadIdx.x) >> 3;
    int c = threadIdx.x & 7;
    if (gg >= NN) return;
    int node = perm[gg];
    int lane = threadIdx.x & 63;
    int base = lane & 56;
    int beg = offs[node], end = offs[node + 1];
    float s[8] = {0.f, 0.f, 0.f, 0.f, 0.f, 0.f, 0.f, 0.f};
    int j = beg;
    for (; j + 16 <= end; j += 16) {
        int va = csr[j + c];
        int vb = csr[j + 8 + c];
        int i0 = __shfl(va, base + 0, 64), i1 = __shfl(va, base + 1, 64);
        int i2 = __shfl(va, base + 2, 64), i3 = __shfl(va, base + 3, 64);
        int i4 = __shfl(va, base + 4, 64), i5 = __shfl(va, base + 5, 64);
        int i6 = __shfl(va, base + 6, 64), i7 = __shfl(va, base + 7, 64);
        int m0 = __shfl(vb, base + 0, 64), m1 = __shfl(vb, base + 1, 64);
        int m2 = __shfl(vb, base + 2, 64), m3 = __shfl(vb, base + 3, 64);
        int m4 = __shfl(vb, base + 4, 64), m5 = __shfl(vb, base + 5, 64);
        int m6 = __shfl(vb, base + 6, 64), m7 = __shfl(vb, base + 7, 64);
        uint4 d0 = inb[i0 * 8 + c], d1 = inb[i1 * 8 + c];
        uint4 d2 = inb[i2 * 8 + c], d3 = inb[i3 * 8 + c];
        uint4 d4 = inb[i4 * 8 + c], d5 = inb[i5 * 8 + c];
        uint4 d6 = inb[i6 * 8 + c], d7 = inb[i7 * 8 + c];
        uint4 e0 = inb[m0 * 8 + c], e1 = inb[m1 * 8 + c];
        uint4 e2 = inb[m2 * 8 + c], e3 = inb[m3 * 8 + c];
        uint4 e4 = inb[m4 * 8 + c], e5 = inb[m5 * 8 + c];
        uint4 e6 = inb[m6 * 8 + c], e7 = inb[m7 * 8 + c];
        add8(s, d0); add8(s, d1); add8(s, d2); add8(s, d3);
        add8(s, d4); add8(s, d5); add8(s, d6); add8(s, d7);
        add8(s, e0); add8(s, e1); add8(s, e2); add8(s, e3);
        add8(s, e4); add8(s, e5); add8(s, e6); add8(s, e7);
    }
    for (; j + 8 <= end; j += 8) {
        int v = csr[j + c];
        int i0 = __shfl(v, base + 0, 64), i1 = __shfl(v, base + 1, 64);
        int i2 = __shfl(v, base + 2, 64), i3 = __shfl(v, base + 3, 64);
        int i4 = __shfl(v, base + 4, 64), i5 = __shfl(v, base + 5, 64);
        int i6 = __shfl(v, base + 6, 64), i7 = __shfl(v, base + 7, 64);
        uint4 d0 = inb[i0 * 8 + c], d1 = inb[i1 * 8 + c];
        uint4 d2 = inb[i2 * 8 + c], d3 = inb[i3 * 8 + c];
        uint4 d4 = inb[i4 * 8 + c], d5 = inb[i5 * 8 + c];
        uint4 d6 = inb[i6 * 8 + c], d7 = inb[i7 * 8 + c];
        add8(s, d0); add8(s, d1); add8(s, d2); add8(s, d3);
        add8(s, d4); add8(s, d5); add8(s, d6); add8(s, d7);
    }
    int rem = end - j;
    if (rem > 0) {
        int v = csr[j + (c < rem ? c : 0)];
        int idx[8];
#pragma unroll
        for (int k = 0; k < 8; ++k) idx[k] = __shfl(v, base + k, 64);
#pragma unroll
        for (int k = 0; k < 8; ++k)
            if (k < rem) { uint4 d = inb[idx[k] * 8 + c]; add8(s, d); }
    }
    int deg = end - beg;
    float inv = (deg > 0) ? 1.f / (float)deg : 0.f;
    uint4 o;
    o.x = bf16rne(s[0] * inv) | (bf16rne(s[1] * inv) << 16);
    o.y = bf16rne(s[2] * inv) | (bf16rne(s[3] * inv) << 16);
    o.z = bf16rne(s[4] * inv) | (bf16rne(s[5] * inv) << 16);
    o.w = bf16rne(s[6] * inv) | (bf16rne(s[7] * inv) << 16);
    hnb[node * 8 + c] = o;
}

// ---------------- unified layer GEMM ----------------
// A and N tiles both from bf16 tables. LAST=false: relu + bf16 out.
// LAST=true: second fused GEMM with Wfc/bfc, fp32 out.

template <bool LAST>
__launch_bounds__(256)
__global__ void k_layer(const uint4* __restrict__ Ab, const uint4* __restrict__ Nhb,
                        const float* __restrict__ Ws, const float* __restrict__ Wn,
                        const float* __restrict__ b,
                        const float* __restrict__ Wfc, const float* __restrict__ bfc,
                        uint2* __restrict__ outb, float* __restrict__ out) {
    __shared__ alignas(16) float AsT[F * AT];
    __shared__ alignas(16) float NsT[F * AT];
    __shared__ alignas(16) float WsL[F * F];
    __shared__ alignas(16) float WnL[F * F];

    const int tid = threadIdx.x;
    const int node0 = blockIdx.x * 64;

    for (int idx = tid; idx < F * F / 4; idx += 256) {
        ((float4*)WsL)[idx] = ((const float4*)Ws)[idx];
        ((float4*)WnL)[idx] = ((const float4*)Wn)[idx];
    }
    for (int idx = tid; idx < 64 * 8; idx += 256) {
        int n = idx >> 3, c = idx & 7;
        int node = node0 + n;
        uint4 a = make_uint4(0u, 0u, 0u, 0u);
        uint4 v = make_uint4(0u, 0u, 0u, 0u);
        if (node < NN) {
            a = Ab[node * 8 + c];
            v = Nhb[node * 8 + c];
        }
        int f = 8 * c;
        AsT[(f + 0) * AT + n] = bflo(a.x); AsT[(f + 1) * AT + n] = bfhi(a.x);
        AsT[(f + 2) * AT + n] = bflo(a.y); AsT[(f + 3) * AT + n] = bfhi(a.y);
        AsT[(f + 4) * AT + n] = bflo(a.z); AsT[(f + 5) * AT + n] = bfhi(a.z);
        AsT[(f + 6) * AT + n] = bflo(a.w); AsT[(f + 7) * AT + n] = bfhi(a.w);
        NsT[(f + 0) * AT + n] = bflo(v.x); NsT[(f + 1) * AT + n] = bfhi(v.x);
        NsT[(f + 2) * AT + n] = bflo(v.y); NsT[(f + 3) * AT + n] = bfhi(v.y);
        NsT[(f + 4) * AT + n] = bflo(v.z); NsT[(f + 5) * AT + n] = bfhi(v.z);
        NsT[(f + 6) * AT + n] = bflo(v.w); NsT[(f + 7) * AT + n] = bfhi(v.w);
    }
    __syncthreads();

    const int tx = tid & 15, ty = tid >> 4;
    float acc[4][4];
#pragma unroll
    for (int j = 0; j < 4; ++j) {
        float bv = b[4 * tx + j];
        acc[0][j] = bv; acc[1][j] = bv; acc[2][j] = bv; acc[3][j] = bv;
    }
#pragma unroll 4
    for (int k = 0; k < 64; ++k) {
        float4 a4 = *(const float4*)&AsT[k * AT + 4 * ty];
        float4 n4 = *(const float4*)&NsT[k * AT + 4 * ty];
        float4 w4 = *(const float4*)&WsL[k * 64 + 4 * tx];
        float4 u4 = *(const float4*)&WnL[k * 64 + 4 * tx];
        float a_[4] = {a4.x, a4.y, a4.z, a4.w};
        float n_[4] = {n4.x, n4.y, n4.z, n4.w};
        float w_[4] = {w4.x, w4.y, w4.z, w4.w};
        float u_[4] = {u4.x, u4.y, u4.z, u4.w};
#pragma unroll
        for (int i = 0; i < 4; ++i)
#pragma unroll
            for (int j = 0; j < 4; ++j)
                acc[i][j] += a_[i] * w_[j] + n_[i] * u_[j];
    }

    if (!LAST) {
#pragma unroll
        for (int i = 0; i < 4; ++i) {
            int node = node0 + 4 * ty + i;
            if (node < NN) {
                float ox = acc[i][0] > 0.f ? acc[i][0] : 0.f;
                float oy = acc[i][1] > 0.f ? acc[i][1] : 0.f;
                float oz = acc[i][2] > 0.f ? acc[i][2] : 0.f;
                float ow = acc[i][3] > 0.f ? acc[i][3] : 0.f;
                uint2 p;
                p.x = bf16rne(ox) | (bf16rne(oy) << 16);
                p.y = bf16rne(oz) | (bf16rne(ow) << 16);
                outb[node * 16 + tx] = p;
            }
        }
    } else {
        // fused final GEMM: h2 tile -> LDS transposed, Wfc -> WsL, GEMM2
        __syncthreads();
#pragma unroll
        for (int i = 0; i < 4; ++i)
#pragma unroll
            for (int j = 0; j < 4; ++j)
                AsT[(4 * tx + j) * AT + (4 * ty + i)] = acc[i][j];
        for (int idx = tid; idx < F * F / 4; idx += 256)
            ((float4*)WsL)[idx] = ((const float4*)Wfc)[idx];
        __syncthreads();

        float acc2[4][4];
#pragma unroll
        for (int j = 0; j < 4; ++j) {
            float bv = bfc[4 * tx + j];
            acc2[0][j] = bv; acc2[1][j] = bv; acc2[2][j] = bv; acc2[3][j] = bv;
        }
#pragma unroll 4
        for (int k = 0; k < 64; ++k) {
            float4 a4 = *(const float4*)&AsT[k * AT + 4 * ty];
            float4 w4 = *(const float4*)&WsL[k * 64 + 4 * tx];
            float a_[4] = {a4.x, a4.y, a4.z, a4.w};
            float w_[4] = {w4.x, w4.y, w4.z, w4.w};
#pragma unroll
            for (int i = 0; i < 4; ++i)
#pragma unroll
                for (int j = 0; j < 4; ++j)
                    acc2[i][j] += a_[i] * w_[j];
        }
#pragma unroll
        for (int i = 0; i < 4; ++i) {
            int node = node0 + 4 * ty + i;
            if (node < NN) {
                float4 o;
                o.x = acc2[i][0]; o.y = acc2[i][1]; o.z = acc2[i][2]; o.w = acc2[i][3];
                *(float4*)&out[node * 64 + 4 * tx] = o;
            }
        }
    }
}

// ---------------- launch ----------------

extern "C" void kernel_launch(void* const* d_in, const int* in_sizes, int n_in,
                              void* d_out, int out_size, void* d_ws, size_t ws_size,
                              hipStream_t stream) {
    const float* embed = (const float*)d_in[0];
    const float* W1s = (const float*)d_in[1];
    const float* W1n = (const float*)d_in[2];
    const float* b1  = (const float*)d_in[3];
    const float* W2s = (const float*)d_in[4];
    const float* W2n = (const float*)d_in[5];
    const float* b2  = (const float*)d_in[6];
    const float* Wfc = (const float*)d_in[7];
    const float* bfc = (const float*)d_in[8];
    const int* ids = (const int*)d_in[9];
    const int* src = (const int*)d_in[10];
    const int* dst = (const int*)d_in[11];
    float* out = (float*)d_out;

    char* ws = (char*)d_ws;
    size_t off = 0;
    auto alloc = [&](size_t nb) {
        char* p = ws + off;
        off = (off + nb + 255) & ~(size_t)255;
        return p;
    };
    int*   cnt      = (int*)alloc(NN * sizeof(int));        // zeroed
    int*   dhist    = (int*)alloc(64 * sizeof(int));        // zeroed
    int*   dcur     = (int*)alloc(64 * sizeof(int));        // zeroed
    size_t zero_bytes = off;
    int*   offs     = (int*)alloc((NN + 1) * sizeof(int));
    int*   partials = (int*)alloc(SCAN_B * sizeof(int));
    int*   perm     = (int*)alloc(NN * sizeof(int));
    int*   pos      = (int*)alloc(NE * sizeof(int));
    int*   csr      = (int*)alloc(NE * sizeof(int));
    uint2* xb       = (uint2*)alloc((size_t)NN * 16 * sizeof(uint2));  // bf16 x
    uint2* h1b      = (uint2*)alloc((size_t)NN * 16 * sizeof(uint2));  // bf16 h1
    uint4* hnb      = (uint4*)alloc((size_t)NN * 8 * sizeof(uint4));   // bf16 agg

    hipMemsetAsync(d_ws, 0, zero_bytes, stream);

    const int TB = 256;
    const int EB = (NE + TB - 1) / TB;     // 3125
    k_count_gather<<<EB, TB, 0, stream>>>(dst, cnt, pos, embed, ids, xb);
    k_scan_a<<<SCAN_B, 256, 0, stream>>>(cnt, partials);
    k_scan_c2<<<SCAN_B, 256, 0, stream>>>(cnt, partials, offs, dhist);
    k_perm<<<(NN + 255) / 256, 256, 0, stream>>>(cnt, dhist, dcur, perm);
    k_fill<<<EB, TB, 0, stream>>>(src, dst, offs, pos, csr);

    const int NB = (NN + 63) / 64;         // 782
    const int AB = (NN * 8 + 255) / 256;   // 1563

    k_aggb<<<AB, TB, 0, stream>>>((const uint4*)xb, offs, csr, perm, hnb);
    k_layer<false><<<NB, TB, 0, stream>>>((const uint4*)xb, hnb, W1s, W1n, b1,
                                          nullptr, nullptr, h1b, nullptr);
    k_aggb<<<AB, TB, 0, stream>>>((const uint4*)h1b, offs, csr, perm, hnb);
    k_layer<true><<<NB, TB, 0, stream>>>((const uint4*)h1b, hnb, W2s, W2n, b2,
                                         Wfc, bfc, nullptr, out);
}

// Round 9
// 232.857 us; speedup vs baseline: 1.2198x; 1.0105x over previous
//
#include <hip/hip_runtime.h>

#define NN 50000      // nodes
#define NE 800000     // edges
#define F  64         // feature dim
#define AT 68         // padded LDS stride (mult of 4, not mult of 32)
#define SCAN_B 49     // scan blocks: 49 * 1024 >= 50000

// bf16 round-to-nearest-even, returns low-16 bits
__device__ __forceinline__ unsigned bf16rne(float f) {
    unsigned u = __float_as_uint(f);
    return (u + 0x7fffu + ((u >> 16) & 1u)) >> 16;
}
__device__ __forceinline__ float bflo(unsigned p) { return __uint_as_float(p << 16); }
__device__ __forceinline__ float bfhi(unsigned p) { return __uint_as_float(p & 0xffff0000u); }

// ---------------- fused: edge degree count+slot  AND  embedding gather ----------------

__launch_bounds__(256)
__global__ void k_count_gather(const int* __restrict__ dst, int* __restrict__ cnt,
                               int* __restrict__ pos,
                               const float* __restrict__ embed, const int* __restrict__ ids,
                               uint2* __restrict__ xb) {
    int t = blockIdx.x * blockDim.x + threadIdx.x;
    if (t < NE) pos[t] = atomicAdd(&cnt[dst[t]], 1);   // coalesced pos write
    if (t < NN * 16) {
        int i = t >> 4, c = t & 15;
        float4 v = ((const float4*)embed)[ids[i] * 16 + c];
        uint2 p;
        p.x = bf16rne(v.x) | (bf16rne(v.y) << 16);
        p.y = bf16rne(v.z) | (bf16rne(v.w) << 16);
        xb[t] = p;
    }
}

// ---- 2-dispatch scan: block partials, then per-block redundant scan of partials ----

__launch_bounds__(256)
__global__ void k_scan_a(const int* __restrict__ cnt, int* __restrict__ partials) {
    __shared__ int sc[256];
    int t = threadIdx.x;
    int base = blockIdx.x * 1024 + t * 4;
    int s = 0;
#pragma unroll
    for (int k = 0; k < 4; ++k) {
        int idx = base + k;
        s += (idx < NN) ? cnt[idx] : 0;
    }
    sc[t] = s;
    __syncthreads();
    for (int d = 128; d > 0; d >>= 1) {
        if (t < d) sc[t] += sc[t + d];
        __syncthreads();
    }
    if (t == 0) partials[blockIdx.x] = sc[0];
}

__launch_bounds__(256)
__global__ void k_scan_c2(const int* __restrict__ cnt, const int* __restrict__ partials,
                          int* __restrict__ offs) {
    __shared__ int sboff;
    __shared__ int stotal;
    __shared__ int sc[256];
    int t = threadIdx.x;
    if (t < 64) {  // wave 0 redundantly scans the 49 partials
        int v = (t < SCAN_B) ? partials[t] : 0;
        int orig = v;
        for (int d = 1; d < 64; d <<= 1) {
            int u = __shfl_up(v, d);
            if (t >= d) v += u;
        }
        if (t == (int)blockIdx.x) sboff = v - orig;
        if (t == 63) stotal = v;
    }
    int base = blockIdx.x * 1024 + t * 4;
    int v4[4];
#pragma unroll
    for (int k = 0; k < 4; ++k) {
        int idx = base + k;
        v4[k] = (idx < NN) ? cnt[idx] : 0;
    }
    int lsum = v4[0] + v4[1] + v4[2] + v4[3];
    sc[t] = lsum;
    __syncthreads();
    for (int d = 1; d < 256; d <<= 1) {
        int u = (t >= d) ? sc[t - d] : 0;
        __syncthreads();
        sc[t] += u;
        __syncthreads();
    }
    int run = sboff + sc[t] - lsum;
#pragma unroll
    for (int k = 0; k < 4; ++k) {
        int idx = base + k;
        if (idx < NN) { offs[idx] = run; run += v4[k]; }
    }
    if (blockIdx.x == 0 && t == 0) offs[NN] = stotal;
}

// atomic-free fill: slot was precomputed in pos[]
__global__ void k_fill(const int* __restrict__ src, const int* __restrict__ dst,
                       const int* __restrict__ offs, const int* __restrict__ pos,
                       int* __restrict__ csr) {
    int e = blockIdx.x * blockDim.x + threadIdx.x;
    if (e < NE) csr[offs[dst[e]] + pos[e]] = src[e];
}

// ---------------- fused layer: aggregate + GEMM in one kernel ----------------
// 512 threads, 64 nodes/block. Agg phase: thread = (node, uint4 chunk), 8 lanes
// per node, unroll-8 gathers with shfl-broadcast indices; result -> NsT (fp32,
// no global round-trip). A-tile unpacked from the bf16 table -> AsT. Weights
// Ws|Wn bf16-packed in one LDS array (one b128 read = both). LDS = 51.2 KB
// -> 3 blocks/CU -> 24 waves/CU during agg.
// LAST=false: relu -> bf16 out. LAST=true: second GEMM with Wfc/bfc -> fp32 out.

__device__ __forceinline__ void add8(float s[8], const uint4 v) {
    s[0] += bflo(v.x); s[1] += bfhi(v.x);
    s[2] += bflo(v.y); s[3] += bfhi(v.y);
    s[4] += bflo(v.z); s[5] += bfhi(v.z);
    s[6] += bflo(v.w); s[7] += bfhi(v.w);
}

template <bool LAST>
__launch_bounds__(512)
__global__ void k_fused(const uint4* __restrict__ Ab, const int* __restrict__ offs,
                        const int* __restrict__ csr,
                        const float* __restrict__ Ws, const float* __restrict__ Wn,
                        const float* __restrict__ b,
                        const float* __restrict__ Wfc, const float* __restrict__ bfc,
                        uint2* __restrict__ outb, float* __restrict__ out) {
    __shared__ alignas(16) float AsT[F * AT];      // self tile, transposed [f][node]
    __shared__ alignas(16) float NsT[F * AT];      // neighbor-mean tile, transposed
    __shared__ alignas(16) unsigned Wpk[F * F];    // Ws|Wn<<16 bf16-packed [k][f]

    const int tid = threadIdx.x;
    const int node0 = blockIdx.x * 64;

    // stage packed weights
    for (int i = tid; i < F * F; i += 512)
        Wpk[i] = bf16rne(Ws[i]) | (bf16rne(Wn[i]) << 16);

    // agg + A-stage: one (node, chunk) item per thread
    {
        const int n = tid >> 3;          // node within tile
        const int c = tid & 7;           // uint4 chunk (8 bf16 feats)
        const int lane = tid & 63;
        const int base = lane & 56;
        const int gnode = node0 + n;
        float s[8] = {0.f, 0.f, 0.f, 0.f, 0.f, 0.f, 0.f, 0.f};
        uint4 a = make_uint4(0u, 0u, 0u, 0u);
        float inv = 0.f;
        if (gnode < NN) {
            a = Ab[gnode * 8 + c];
            int beg = offs[gnode], end = offs[gnode + 1];
            int j = beg;
            for (; j + 8 <= end; j += 8) {
                int v = csr[j + c];
                int i0 = __shfl(v, base + 0, 64), i1 = __shfl(v, base + 1, 64);
                int i2 = __shfl(v, base + 2, 64), i3 = __shfl(v, base + 3, 64);
                int i4 = __shfl(v, base + 4, 64), i5 = __shfl(v, base + 5, 64);
                int i6 = __shfl(v, base + 6, 64), i7 = __shfl(v, base + 7, 64);
                uint4 d0 = Ab[i0 * 8 + c], d1 = Ab[i1 * 8 + c];
                uint4 d2 = Ab[i2 * 8 + c], d3 = Ab[i3 * 8 + c];
                uint4 d4 = Ab[i4 * 8 + c], d5 = Ab[i5 * 8 + c];
                uint4 d6 = Ab[i6 * 8 + c], d7 = Ab[i7 * 8 + c];
                add8(s, d0); add8(s, d1); add8(s, d2); add8(s, d3);
                add8(s, d4); add8(s, d5); add8(s, d6); add8(s, d7);
            }
            int rem = end - j;
            if (rem > 0) {
                int v = csr[j + (c < rem ? c : 0)];
                int idx[8];
#pragma unroll
                for (int k = 0; k < 8; ++k) idx[k] = __shfl(v, base + k, 64);
#pragma unroll
                for (int k = 0; k < 8; ++k)
                    if (k < rem) { uint4 d = Ab[idx[k] * 8 + c]; add8(s, d); }
            }
            int deg = end - beg;
            inv = (deg > 0) ? 1.f / (float)deg : 0.f;
        }
        int f = 8 * c;
        AsT[(f + 0) * AT + n] = bflo(a.x); AsT[(f + 1) * AT + n] = bfhi(a.x);
        AsT[(f + 2) * AT + n] = bflo(a.y); AsT[(f + 3) * AT + n] = bfhi(a.y);
        AsT[(f + 4) * AT + n] = bflo(a.z); AsT[(f + 5) * AT + n] = bfhi(a.z);
        AsT[(f + 6) * AT + n] = bflo(a.w); AsT[(f + 7) * AT + n] = bfhi(a.w);
#pragma unroll
        for (int q = 0; q < 8; ++q) NsT[(f + q) * AT + n] = s[q] * inv;
    }
    __syncthreads();

    // GEMM: 512 threads = 16(feat-grp) x 32(node-grp); microtile 2 nodes x 4 feats
    const int tx = tid & 15, ty = tid >> 4;
    float acc[2][4];
#pragma unroll
    for (int j = 0; j < 4; ++j) {
        float bv = b[4 * tx + j];
        acc[0][j] = bv; acc[1][j] = bv;
    }
#pragma unroll 4
    for (int k = 0; k < 64; ++k) {
        float2 a2 = *(const float2*)&AsT[k * AT + 2 * ty];
        float2 n2 = *(const float2*)&NsT[k * AT + 2 * ty];
        uint4 wq = *(const uint4*)&Wpk[k * 64 + 4 * tx];
        float ws_[4] = {bflo(wq.x), bflo(wq.y), bflo(wq.z), bflo(wq.w)};
        float wn_[4] = {bfhi(wq.x), bfhi(wq.y), bfhi(wq.z), bfhi(wq.w)};
        float a_[2] = {a2.x, a2.y};
        float n_[2] = {n2.x, n2.y};
#pragma unroll
        for (int i = 0; i < 2; ++i)
#pragma unroll
            for (int j = 0; j < 4; ++j)
                acc[i][j] += a_[i] * ws_[j] + n_[i] * wn_[j];
    }

    if (!LAST) {
#pragma unroll
        for (int i = 0; i < 2; ++i) {
            int node = node0 + 2 * ty + i;
            if (node < NN) {
                float o0 = acc[i][0] > 0.f ? acc[i][0] : 0.f;
                float o1 = acc[i][1] > 0.f ? acc[i][1] : 0.f;
                float o2 = acc[i][2] > 0.f ? acc[i][2] : 0.f;
                float o3 = acc[i][3] > 0.f ? acc[i][3] : 0.f;
                uint2 p;
                p.x = bf16rne(o0) | (bf16rne(o1) << 16);
                p.y = bf16rne(o2) | (bf16rne(o3) << 16);
                outb[node * 16 + tx] = p;
            }
        }
    } else {
        // fused final GEMM: h2 tile -> AsT transposed; Wfc (fp32) reuses Wpk storage
        __syncthreads();
        float* Wf = (float*)Wpk;
#pragma unroll
        for (int i = 0; i < 2; ++i)
#pragma unroll
            for (int j = 0; j < 4; ++j)
                AsT[(4 * tx + j) * AT + (2 * ty + i)] = acc[i][j];
        for (int i = tid; i < F * F / 4; i += 512)
            ((float4*)Wf)[i] = ((const float4*)Wfc)[i];
        __syncthreads();

        float acc2[2][4];
#pragma unroll
        for (int j = 0; j < 4; ++j) {
            float bv = bfc[4 * tx + j];
            acc2[0][j] = bv; acc2[1][j] = bv;
        }
#pragma unroll 4
        for (int k = 0; k < 64; ++k) {
            float2 a2 = *(const float2*)&AsT[k * AT + 2 * ty];
            float4 w4 = *(const float4*)&Wf[k * 64 + 4 * tx];
            float a_[2] = {a2.x, a2.y};
            float w_[4] = {w4.x, w4.y, w4.z, w4.w};
#pragma unroll
            for (int i = 0; i < 2; ++i)
#pragma unroll
                for (int j = 0; j < 4; ++j)
                    acc2[i][j] += a_[i] * w_[j];
        }
#pragma unroll
        for (int i = 0; i < 2; ++i) {
            int node = node0 + 2 * ty + i;
            if (node < NN) {
                float4 o;
                o.x = acc2[i][0]; o.y = acc2[i][1]; o.z = acc2[i][2]; o.w = acc2[i][3];
                *(float4*)&out[node * 64 + 4 * tx] = o;
            }
        }
    }
}

// ---------------- launch ----------------

extern "C" void kernel_launch(void* const* d_in, const int* in_sizes, int n_in,
                              void* d_out, int out_size, void* d_ws, size_t ws_size,
                              hipStream_t stream) {
    const float* embed = (const float*)d_in[0];
    const float* W1s = (const float*)d_in[1];
    const float* W1n = (const float*)d_in[2];
    const float* b1  = (const float*)d_in[3];
    const float* W2s = (const float*)d_in[4];
    const float* W2n = (const float*)d_in[5];
    const float* b2  = (const float*)d_in[6];
    const float* Wfc = (const float*)d_in[7];
    const float* bfc = (const float*)d_in[8];
    const int* ids = (const int*)d_in[9];
    const int* src = (const int*)d_in[10];
    const int* dst = (const int*)d_in[11];
    float* out = (float*)d_out;

    char* ws = (char*)d_ws;
    size_t off = 0;
    auto alloc = [&](size_t nb) {
        char* p = ws + off;
        off = (off + nb + 255) & ~(size_t)255;
        return p;
    };
    int*   cnt      = (int*)alloc(NN * sizeof(int));        // zeroed
    size_t zero_bytes = off;
    int*   offs     = (int*)alloc((NN + 1) * sizeof(int));
    int*   partials = (int*)alloc(SCAN_B * sizeof(int));
    int*   pos      = (int*)alloc(NE * sizeof(int));
    int*   csr      = (int*)alloc(NE * sizeof(int));
    uint2* xb       = (uint2*)alloc((size_t)NN * 16 * sizeof(uint2));  // bf16 x
    uint2* h1b      = (uint2*)alloc((size_t)NN * 16 * sizeof(uint2));  // bf16 h1

    hipMemsetAsync(d_ws, 0, zero_bytes, stream);

    const int TB = 256;
    const int EB = (NE + TB - 1) / TB;     // 3125
    k_count_gather<<<EB, TB, 0, stream>>>(dst, cnt, pos, embed, ids, xb);
    k_scan_a<<<SCAN_B, 256, 0, stream>>>(cnt, partials);
    k_scan_c2<<<SCAN_B, 256, 0, stream>>>(cnt, partials, offs);
    k_fill<<<EB, TB, 0, stream>>>(src, dst, offs, pos, csr);

    const int NB = (NN + 63) / 64;         // 782
    k_fused<false><<<NB, 512, 0, stream>>>((const uint4*)xb, offs, csr,
                                           W1s, W1n, b1, nullptr, nullptr,
                                           h1b, nullptr);
    k_fused<true><<<NB, 512, 0, stream>>>((const uint4*)h1b, offs, csr,
                                          W2s, W2n, b2, Wfc, bfc,
                                          nullptr, out);
}